// Round 10
// baseline (133.094 us; speedup 1.0000x reference)
//
#include <hip/hip_runtime.h>

// Neo-Hookean constants (match reference)
#define MU_C   3846.1538461538462f   // E/(2(1+nu))
#define LM_C   5769.2307692307695f   // E*nu/((1+nu)(1-2nu))
#define LOGC   (MU_C + 0.5f * LM_C)  // combined log coefficient
#define EPS_C  1e-10f

// v9: persistent blocks + double-buffered LDS staging (T14 async-split) +
// register-double-buffered ut gathers pipelined one tile ahead.
// Tile = 64 elements. Thread = (element p = t>>2, batch b = t&3).
#define NB_TARGET 1024   // 4 blocks/CU resident (LDS 32KB, VGPR<=128)

// Transpose u (B, n_nodes, 3) -> ut (n_nodes, B, 4) padded float4 (64B/node).
__global__ __launch_bounds__(256) void nh_transpose_u_pad(
    const float* __restrict__ u, float4* __restrict__ ut, int n_nodes)
{
    const int i = blockIdx.x * 256 + threadIdx.x;
    if (i >= n_nodes) return;
    float4* q = ut + (size_t)i * 4;
    #pragma unroll
    for (int b = 0; b < 4; ++b) {
        const float* p = u + ((size_t)b * n_nodes + i) * 3;
        q[b] = make_float4(p[0], p[1], p[2], 0.f);
    }
}

// energy of one element/batch: dN slab from LDS (13-f4 padded), u from regs
__device__ __forceinline__ float nh_energy_lds(
    const float4* slab,            // [q*3 + k], padded stride handled by caller
    const float4& u0, const float4& u1, const float4& u2, const float4& u3,
    const float* wq)
{
    const float un[4][3] = {{u0.x, u0.y, u0.z}, {u1.x, u1.y, u1.z},
                            {u2.x, u2.y, u2.z}, {u3.x, u3.y, u3.z}};
    float a = 0.f;
    #pragma unroll
    for (int q = 0; q < 4; ++q) {
        const float4 f0 = slab[q*3 + 0];
        const float4 f1 = slab[q*3 + 1];
        const float4 f2 = slab[q*3 + 2];
        const float d[12] = {f0.x,f0.y,f0.z,f0.w, f1.x,f1.y,f1.z,f1.w,
                             f2.x,f2.y,f2.z,f2.w};   // d[n*3 + j]
        float F[3][3];
        #pragma unroll
        for (int i = 0; i < 3; ++i) {
            #pragma unroll
            for (int j = 0; j < 3; ++j) {
                float g = 0.f;
                #pragma unroll
                for (int n = 0; n < 4; ++n)
                    g = fmaf(un[n][i], d[n*3 + j], g);
                F[i][j] = g + ((i == j) ? 1.f : 0.f);
            }
        }
        const float J =
              F[0][0] * (F[1][1]*F[2][2] - F[1][2]*F[2][1])
            - F[0][1] * (F[1][0]*F[2][2] - F[1][2]*F[2][0])
            + F[0][2] * (F[1][0]*F[2][1] - F[1][1]*F[2][0]);
        float IC = 0.f;
        #pragma unroll
        for (int i = 0; i < 3; ++i)
            #pragma unroll
            for (int j = 0; j < 3; ++j)
                IC = fmaf(F[i][j], F[i][j], IC);
        const float lj = __logf(fmaxf(J, EPS_C));
        const float W = 0.5f * MU_C * (IC - 3.f)
                      + 0.25f * LM_C * fmaf(J, J, -1.f)
                      - LOGC * lj;
        a = fmaf(W, wq[q], a);
    }
    return a;
}

__global__ __launch_bounds__(256, 4) void nh_partial_v9(
    const float4* __restrict__ ut,        // (n_nodes, 4) padded float4
    const int4*   __restrict__ elp,       // (n_elem) int4
    const float4* __restrict__ dnp,       // (n_elem*12) float4
    const float4* __restrict__ djp,       // (n_elem) float4
    const float*  __restrict__ qw,        // (4,)
    float* __restrict__ partial,          // (gridDim.x, 4)
    int n_elem, int ntiles, int chunk)
{
    __shared__ float4 s_dn[2][64 * 13];   // padded: 2-way bank conflicts only
    __shared__ float4 s_dj[2][64];
    __shared__ int4   s_el[3][64];
    __shared__ float  s_red[4][4];

    const int t = threadIdx.x;
    const int b = t & 3;
    const int p = t >> 2;

    const int t0  = blockIdx.x * chunk;
    const int t1  = min(t0 + chunk, ntiles);
    const int cnt = t1 - t0;

    if (cnt <= 0) {
        if (t < 4) partial[(size_t)blockIdx.x * 4 + t] = 0.f;
        return;
    }

    const int tlast  = t1 - 1;
    const int nf4max = n_elem * 12 - 1;
    const int nelmax = n_elem - 1;
    const float4 w4  = *reinterpret_cast<const float4*>(qw);

    // hoisted staging destinations (padded slab scatter)
    const int oA = (t       / 12) * 13 + (t       % 12);
    const int oB = ((t+256) / 12) * 13 + ((t+256) % 12);
    const int oC = ((t+512) / 12) * 13 + ((t+512) % 12);

    float acc = 0.f;

    // ---------------- prologue: tile t0 -> buf0; el slots 0,1 ----------------
    {
        float4 r0, r1, r2, rdj; int4 rel0, rel1;
        const int base = t0 * 768;
        r0 = dnp[min(base + t,       nf4max)];
        r1 = dnp[min(base + t + 256, nf4max)];
        r2 = dnp[min(base + t + 512, nf4max)];
        if (t < 64) {
            rel0 = elp[min(t0 * 64 + t, nelmax)];
            rel1 = elp[min(min(t0 + 1, tlast) * 64 + t, nelmax)];
        } else if (t < 128) {
            rdj = djp[min(t0 * 64 + (t - 64), nelmax)];
        }
        s_dn[0][oA] = r0; s_dn[0][oB] = r1; s_dn[0][oC] = r2;
        if (t < 64)       { s_el[0][t] = rel0; s_el[1][t] = rel1; }
        else if (t < 128) { s_dj[0][t - 64] = rdj; }
        __syncthreads();
    }

    // prologue gather for tile t0 (one exposed latency per block)
    float4 uA0, uA1, uA2, uA3, uB0, uB1, uB2, uB3;
    {
        const int4 nd = s_el[0][p];
        uA0 = ut[nd.x * 4 + b]; uA1 = ut[nd.y * 4 + b];
        uA2 = ut[nd.z * 4 + b]; uA3 = ut[nd.w * 4 + b];
    }

    // one pipeline body: stage M+1, gather M+1 into V*, compute M with U*
    #define NH_BODY(M, CC, U0,U1,U2,U3, V0,V1,V2,V3)                          \
    {                                                                         \
        /* A: issue stage loads: dN/dj for tile M+1, el for tile M+2 */       \
        const int tn  = min(t0 + (M) + 1, tlast);                             \
        const int te2 = min(t0 + (M) + 2, tlast);                             \
        float4 r0, r1, r2, rdj; int4 rel;                                     \
        {                                                                     \
            const int base = tn * 768;                                        \
            r0 = dnp[min(base + t,       nf4max)];                            \
            r1 = dnp[min(base + t + 256, nf4max)];                            \
            r2 = dnp[min(base + t + 512, nf4max)];                            \
            if (t < 64)       rel = elp[min(te2 * 64 + t, nelmax)];           \
            else if (t < 128) rdj = djp[min(tn * 64 + (t - 64), nelmax)];     \
        }                                                                     \
        __builtin_amdgcn_sched_barrier(0);                                    \
        /* G: gathers for tile M+1 (el already in LDS) */                     \
        {                                                                     \
            const int4 nd = s_el[((M) + 1) % 3][p];                           \
            V0 = ut[nd.x * 4 + b]; V1 = ut[nd.y * 4 + b];                     \
            V2 = ut[nd.z * 4 + b]; V3 = ut[nd.w * 4 + b];                     \
        }                                                                     \
        __builtin_amdgcn_sched_barrier(0);                                    \
        /* B: compute tile M from buf CC */                                   \
        {                                                                     \
            const int tile = t0 + (M);                                        \
            const float sc = ((M) < cnt && tile * 64 + p < n_elem) ? 1.f : 0.f;\
            const float4 dj4 = s_dj[CC][p];                                   \
            const float wq[4] = {dj4.x * w4.x * sc, dj4.y * w4.y * sc,        \
                                 dj4.z * w4.z * sc, dj4.w * w4.w * sc};       \
            acc += nh_energy_lds(&s_dn[CC][p * 13], U0, U1, U2, U3, wq);      \
        }                                                                     \
        /* C: write staged data to the alternate buffers */                   \
        s_dn[(CC) ^ 1][oA] = r0;                                              \
        s_dn[(CC) ^ 1][oB] = r1;                                              \
        s_dn[(CC) ^ 1][oC] = r2;                                              \
        if (t < 64)       s_el[((M) + 2) % 3][t] = rel;                       \
        else if (t < 128) s_dj[(CC) ^ 1][t - 64] = rdj;                       \
        __syncthreads();                                                      \
    }

    const int iters = (cnt + 1) & ~1;   // even body count, uniform per block
    for (int m = 0; m < iters; m += 2) {
        NH_BODY(m,     0, uA0,uA1,uA2,uA3, uB0,uB1,uB2,uB3)
        NH_BODY(m + 1, 1, uB0,uB1,uB2,uB3, uA0,uA1,uA2,uA3)
    }
    #undef NH_BODY

    // reduce across lanes with the same b (stride-4 groups)
    #pragma unroll
    for (int off = 32; off >= 4; off >>= 1)
        acc += __shfl_down(acc, off);

    const int lane = t & 63;
    const int wid  = t >> 6;
    if (lane < 4) s_red[wid][lane] = acc;
    __syncthreads();
    if (t < 4)
        partial[(size_t)blockIdx.x * 4 + t] =
            (s_red[0][t] + s_red[1][t]) + (s_red[2][t] + s_red[3][t]);
}

__global__ __launch_bounds__(256) void nh_final(
    const float* __restrict__ partial,  // (nparts, 4)
    float* __restrict__ out,            // (4,)
    int nparts)
{
    float accb[4] = {0.f, 0.f, 0.f, 0.f};
    for (int i = threadIdx.x; i < nparts; i += 256) {
        const float4 p = reinterpret_cast<const float4*>(partial)[i];
        accb[0] += p.x; accb[1] += p.y; accb[2] += p.z; accb[3] += p.w;
    }

    #pragma unroll
    for (int b = 0; b < 4; ++b) {
        float v = accb[b];
        #pragma unroll
        for (int off = 32; off > 0; off >>= 1)
            v += __shfl_down(v, off);
        accb[b] = v;
    }

    __shared__ float lds[4][4];
    const int lane = threadIdx.x & 63;
    const int wid  = threadIdx.x >> 6;
    if (lane == 0) {
        #pragma unroll
        for (int b = 0; b < 4; ++b) lds[wid][b] = accb[b];
    }
    __syncthreads();
    if (threadIdx.x == 0) {
        #pragma unroll
        for (int b = 0; b < 4; ++b)
            out[b] = (lds[0][b] + lds[1][b]) + (lds[2][b] + lds[3][b]);
    }
}

extern "C" void kernel_launch(void* const* d_in, const int* in_sizes, int n_in,
                              void* d_out, int out_size, void* d_ws, size_t ws_size,
                              hipStream_t stream) {
    const float* u        = (const float*)d_in[0];
    const int*   elements = (const int*)d_in[1];
    const float* dN_dx    = (const float*)d_in[2];
    const float* detJ     = (const float*)d_in[3];
    const float* qw       = (const float*)d_in[4];
    float* out = (float*)d_out;

    const int B       = out_size;            // 4
    const int n_nodes = in_sizes[0] / (3 * B);
    const int n_elem  = in_sizes[1] / 4;

    const int threads = 256;
    const int ntiles  = (n_elem + 63) / 64;
    const int nblocks = (ntiles < NB_TARGET) ? ntiles : NB_TARGET;
    const int chunk   = (ntiles + nblocks - 1) / nblocks;

    const size_t ut_bytes = (size_t)n_nodes * 4 * sizeof(float4);  // padded
    float4* ut     = (float4*)d_ws;
    float* partial = (float*)((char*)d_ws + ut_bytes);

    const int tb = (n_nodes + threads - 1) / threads;
    nh_transpose_u_pad<<<tb, threads, 0, stream>>>(u, ut, n_nodes);

    nh_partial_v9<<<nblocks, threads, 0, stream>>>(
        ut, reinterpret_cast<const int4*>(elements),
        reinterpret_cast<const float4*>(dN_dx),
        reinterpret_cast<const float4*>(detJ),
        qw, partial, n_elem, ntiles, chunk);

    nh_final<<<1, threads, 0, stream>>>(partial, out, nblocks);
}

// Round 11
// 58.237 us; speedup vs baseline: 2.2854x; 2.2854x over previous
//
#include <hip/hip_runtime.h>

// Neo-Hookean constants (match reference)
#define MU_C   3846.1538461538462f   // E/(2(1+nu))
#define LM_C   5769.2307692307695f   // E*nu/((1+nu)(1-2nu))
#define LOGC   (MU_C + 0.5f * LM_C)  // combined log coefficient
#define EPS_C  1e-10f

// v10 = v6's register 2-slot pipeline  ×  v8's persistent residency.
// Thread = (element, batch). Tile = 64 elements. 1024 contiguous-chunk blocks,
// all resident at once (no churn). Loads for tile m+2 issue during compute of
// tile m; all slot registers named (compile-time indexed), guards uniform.
#define NBLK 1024

// Transpose u (B, n_nodes, 3) -> ut (n_nodes, B, 4) padded float4 (64B/node).
__global__ __launch_bounds__(256) void nh_transpose_u_pad(
    const float* __restrict__ u, float4* __restrict__ ut, int n_nodes)
{
    const int i = blockIdx.x * 256 + threadIdx.x;
    if (i >= n_nodes) return;
    float4* q = ut + (size_t)i * 4;
    #pragma unroll
    for (int b = 0; b < 4; ++b) {
        const float* p = u + ((size_t)b * n_nodes + i) * 3;
        q[b] = make_float4(p[0], p[1], p[2], 0.f);
    }
}

// energy of one element/batch from registers
__device__ __forceinline__ float nh_energy(
    const float4* dn,      // 12 float4 = 48-float dN slab, d[(q*4+n)*3+j]
    const float4* uu,      // 4 float4 node displacements (xyz used)
    const float*  wqv)     // detJ*qw per quad point (0 for invalid elems)
{
    const float* d  = reinterpret_cast<const float*>(dn);
    const float* us = reinterpret_cast<const float*>(uu);
    float a = 0.f;
    #pragma unroll
    for (int q = 0; q < 4; ++q) {
        float F[3][3];
        #pragma unroll
        for (int i = 0; i < 3; ++i) {
            #pragma unroll
            for (int j = 0; j < 3; ++j) {
                float g = 0.f;
                #pragma unroll
                for (int n = 0; n < 4; ++n)
                    g = fmaf(us[n * 4 + i], d[(q*4 + n)*3 + j], g);
                F[i][j] = g + ((i == j) ? 1.f : 0.f);
            }
        }
        const float J =
              F[0][0] * (F[1][1]*F[2][2] - F[1][2]*F[2][1])
            - F[0][1] * (F[1][0]*F[2][2] - F[1][2]*F[2][0])
            + F[0][2] * (F[1][0]*F[2][1] - F[1][1]*F[2][0]);
        float IC = 0.f;
        #pragma unroll
        for (int i = 0; i < 3; ++i)
            #pragma unroll
            for (int j = 0; j < 3; ++j)
                IC = fmaf(F[i][j], F[i][j], IC);
        const float lj = __logf(fmaxf(J, EPS_C));
        const float W = 0.5f * MU_C * (IC - 3.f)
                      + 0.25f * LM_C * fmaf(J, J, -1.f)
                      - LOGC * lj;
        a = fmaf(W, wqv[q], a);
    }
    return a;
}

__global__ __launch_bounds__(256) void nh_partial_v10(
    const float4* __restrict__ ut,        // (n_nodes, 4) padded float4
    const int4*   __restrict__ elp,       // (n_elem) int4
    const float4* __restrict__ dnp,       // (n_elem*12) float4
    const float4* __restrict__ djp,       // (n_elem) float4
    const float*  __restrict__ qw,        // (4,)
    float* __restrict__ partial,          // (gridDim.x, 4)
    int n_elem, int ntiles, int chunk)
{
    const int t = threadIdx.x;
    const int b = t & 3;
    const int p = t >> 2;                 // element-within-tile: 0..63
    const int t0  = blockIdx.x * chunk;
    const int cnt = min(chunk, ntiles - t0);

    __shared__ float s_red[4][4];

    float acc = 0.f;

    if (cnt > 0) {
        const float4 w4 = *reinterpret_cast<const float4*>(qw);
        const int nelmax = n_elem - 1;

        // two named pipeline slots (all indices compile-time)
        float4 dnA[12], dnB[12];
        float4 uuA[4],  uuB[4];
        float  wqA[4],  wqB[4];

        // load slot: element-indexed loads + dependent gathers + folded weights
        #define NH_LOAD(DN, UU, WQ, M)                                        \
        {                                                                     \
            const int e  = (t0 + (M)) * 64 + p;                               \
            const int ec = min(e, nelmax);                                    \
            const int4   nd = elp[ec];                                        \
            const float4 dj = djp[ec];                                        \
            const float4* dptr = dnp + (size_t)ec * 12;                       \
            _Pragma("unroll")                                                 \
            for (int k = 0; k < 12; ++k) DN[k] = dptr[k];                     \
            UU[0] = ut[nd.x * 4 + b];                                         \
            UU[1] = ut[nd.y * 4 + b];                                         \
            UU[2] = ut[nd.z * 4 + b];                                         \
            UU[3] = ut[nd.w * 4 + b];                                         \
            const float vs = (e < n_elem) ? 1.f : 0.f;                        \
            WQ[0] = dj.x * w4.x * vs; WQ[1] = dj.y * w4.y * vs;               \
            WQ[2] = dj.z * w4.z * vs; WQ[3] = dj.w * w4.w * vs;               \
        }

        // prologue
        NH_LOAD(dnA, uuA, wqA, 0)
        if (cnt > 1) NH_LOAD(dnB, uuB, wqB, 1)

        // steady state: compute slot, then refill it two tiles ahead.
        // all guards are block-uniform (t0, cnt, m are scalar).
        for (int m = 0; m < cnt; m += 2) {
            acc += nh_energy(dnA, uuA, wqA);
            if (m + 2 < cnt) NH_LOAD(dnA, uuA, wqA, m + 2)
            if (m + 1 < cnt) acc += nh_energy(dnB, uuB, wqB);
            if (m + 3 < cnt) NH_LOAD(dnB, uuB, wqB, m + 3)
        }
        #undef NH_LOAD
    }

    // reduce across lanes with the same b (stride-4 groups): offsets 32..4
    #pragma unroll
    for (int off = 32; off >= 4; off >>= 1)
        acc += __shfl_down(acc, off);
    // lanes 0..3 now hold this wave's batch sums

    const int lane = t & 63;
    const int wid  = t >> 6;
    if (lane < 4) s_red[wid][lane] = acc;
    __syncthreads();
    if (t < 4)
        partial[(size_t)blockIdx.x * 4 + t] =
            (s_red[0][t] + s_red[1][t]) + (s_red[2][t] + s_red[3][t]);
}

__global__ __launch_bounds__(256) void nh_final(
    const float* __restrict__ partial,  // (nparts, 4)
    float* __restrict__ out,            // (4,)
    int nparts)
{
    float accb[4] = {0.f, 0.f, 0.f, 0.f};
    for (int i = threadIdx.x; i < nparts; i += 256) {
        const float4 p = reinterpret_cast<const float4*>(partial)[i];
        accb[0] += p.x; accb[1] += p.y; accb[2] += p.z; accb[3] += p.w;
    }

    #pragma unroll
    for (int b = 0; b < 4; ++b) {
        float v = accb[b];
        #pragma unroll
        for (int off = 32; off > 0; off >>= 1)
            v += __shfl_down(v, off);
        accb[b] = v;
    }

    __shared__ float lds[4][4];
    const int lane = threadIdx.x & 63;
    const int wid  = threadIdx.x >> 6;
    if (lane == 0) {
        #pragma unroll
        for (int b = 0; b < 4; ++b) lds[wid][b] = accb[b];
    }
    __syncthreads();
    if (threadIdx.x == 0) {
        #pragma unroll
        for (int b = 0; b < 4; ++b)
            out[b] = (lds[0][b] + lds[1][b]) + (lds[2][b] + lds[3][b]);
    }
}

extern "C" void kernel_launch(void* const* d_in, const int* in_sizes, int n_in,
                              void* d_out, int out_size, void* d_ws, size_t ws_size,
                              hipStream_t stream) {
    const float* u        = (const float*)d_in[0];
    const int*   elements = (const int*)d_in[1];
    const float* dN_dx    = (const float*)d_in[2];
    const float* detJ     = (const float*)d_in[3];
    const float* qw       = (const float*)d_in[4];
    float* out = (float*)d_out;

    const int B       = out_size;            // 4
    const int n_nodes = in_sizes[0] / (3 * B);
    const int n_elem  = in_sizes[1] / 4;

    const int threads = 256;
    const int ntiles  = (n_elem + 63) / 64;
    const int nblocks = (ntiles < NBLK) ? ntiles : NBLK;
    const int chunk   = (ntiles + nblocks - 1) / nblocks;

    const size_t ut_bytes = (size_t)n_nodes * 4 * sizeof(float4);  // padded
    float4* ut     = (float4*)d_ws;
    float* partial = (float*)((char*)d_ws + ut_bytes);

    const int tb = (n_nodes + threads - 1) / threads;
    nh_transpose_u_pad<<<tb, threads, 0, stream>>>(u, ut, n_nodes);

    nh_partial_v10<<<nblocks, threads, 0, stream>>>(
        ut, reinterpret_cast<const int4*>(elements),
        reinterpret_cast<const float4*>(dN_dx),
        reinterpret_cast<const float4*>(detJ),
        qw, partial, n_elem, ntiles, chunk);

    nh_final<<<1, threads, 0, stream>>>(partial, out, nblocks);
}